// Round 1
// baseline (305.704 us; speedup 1.0000x reference)
//
#include <hip/hip_runtime.h>
#include <hip/hip_bf16.h>

typedef short short8 __attribute__((ext_vector_type(8)));
typedef float floatx4 __attribute__((ext_vector_type(4)));

constexpr int BATCH = 8, SEQ = 2048, DIMC = 512, HID = 1024, QKD = 128, NHID = 2176;
constexpr int TOK = BATCH * SEQ;

// workspace layout (bytes), all sizes multiples of 1024
constexpr size_t OFF_XN  = 0;                                   // [TOK][512] bf16
constexpr size_t OFF_WHT = OFF_XN  + (size_t)TOK * DIMC * 2;    // [2176][512] bf16 (W_hid^T)
constexpr size_t OFF_WOT = OFF_WHT + (size_t)NHID * DIMC * 2;   // [512][1024] bf16 (W_out^T)
constexpr size_t OFF_UV  = OFF_WOT + (size_t)DIMC * HID * 2;    // [TOK][2176] bf16 (silu(xn@Wh+bh))
constexpr size_t OFF_Q   = OFF_UV  + (size_t)TOK * NHID * 2;    // [TOK][128] bf16
constexpr size_t OFF_K   = OFF_Q   + (size_t)TOK * QKD * 2;     // [TOK][128] bf16 (masked keys zeroed)
constexpr size_t OFF_VT  = OFF_K   + (size_t)TOK * QKD * 2;     // [B][1024][2048] bf16 (V^T per batch)
constexpr size_t OFF_P   = OFF_VT  + (size_t)BATCH * HID * SEQ * 2; // [B][2048][2048] bf16
constexpr size_t OFF_HU  = OFF_P   + (size_t)BATCH * SEQ * SEQ * 2; // [TOK][1024] bf16 ((attn@v)*u)
// total ~223 MiB

// ---------------- LayerNorm: x[T][512] f32 -> xn bf16 ----------------
__global__ __launch_bounds__(256) void ln_kernel(const float* __restrict__ x,
                                                 const float* __restrict__ w,
                                                 const float* __restrict__ b,
                                                 __hip_bfloat16* __restrict__ xn) {
    int t = blockIdx.x;
    const float* xr = x + (size_t)t * DIMC;
    float2 v = ((const float2*)xr)[threadIdx.x];
    float s = v.x + v.y;
    float ss = v.x * v.x + v.y * v.y;
    for (int o = 32; o; o >>= 1) { s += __shfl_down(s, o); ss += __shfl_down(ss, o); }
    __shared__ float red[8];
    int wid = threadIdx.x >> 6, lane = threadIdx.x & 63;
    if (lane == 0) { red[wid] = s; red[4 + wid] = ss; }
    __syncthreads();
    if (threadIdx.x == 0) {
        float a = red[0] + red[1] + red[2] + red[3];
        float q = red[4] + red[5] + red[6] + red[7];
        float mu = a * (1.0f / DIMC);
        red[0] = mu;
        red[4] = q * (1.0f / DIMC) - mu * mu;
    }
    __syncthreads();
    float mu = red[0];
    float inv = rsqrtf(red[4] + 1e-5f);
    int c = threadIdx.x * 2;
    float y0 = (v.x - mu) * inv * w[c] + b[c];
    float y1 = (v.y - mu) * inv * w[c + 1] + b[c + 1];
    __hip_bfloat16* o = xn + (size_t)t * DIMC + c;
    o[0] = __float2bfloat16(y0);
    o[1] = __float2bfloat16(y1);
}

// ------------- weight convert+transpose: WhT[n][k], WoT[d][h] -------------
__global__ __launch_bounds__(256) void cvt_kernel(const float* __restrict__ Wh,
                                                  const float* __restrict__ Wo,
                                                  __hip_bfloat16* __restrict__ WhT,
                                                  __hip_bfloat16* __restrict__ WoT) {
    int i = blockIdx.x * 256 + threadIdx.x;
    const int total1 = NHID * DIMC;          // 1,114,112
    const int total2 = DIMC * HID;           //   524,288
    if (i < total1) {
        int n = i / DIMC, k = i % DIMC;
        WhT[i] = __float2bfloat16(Wh[(size_t)k * NHID + n]);
    } else if (i < total1 + total2) {
        int j = i - total1;
        int d = j / HID, h = j % HID;
        WoT[j] = __float2bfloat16(Wo[(size_t)h * DIMC + d]);
    }
}

// ------------- q/k: gamma/beta + rotary + key-mask-zero -------------
__global__ __launch_bounds__(256) void qkrot_kernel(const __hip_bfloat16* __restrict__ uv,
                                                    const float* __restrict__ sn,
                                                    const float* __restrict__ cs,
                                                    const int* __restrict__ mask,
                                                    const float* __restrict__ gamma,
                                                    const float* __restrict__ beta,
                                                    __hip_bfloat16* __restrict__ q,
                                                    __hip_bfloat16* __restrict__ k) {
    int t = blockIdx.x * 4 + (threadIdx.x >> 6);
    int j = threadIdx.x & 63;
    const __hip_bfloat16* base = uv + (size_t)t * NHID + 2 * HID;
    float b0 = __bfloat162float(base[2 * j]);
    float b1 = __bfloat162float(base[2 * j + 1]);
    float q0 = b0 * gamma[2 * j] + beta[2 * j];
    float q1 = b1 * gamma[2 * j + 1] + beta[2 * j + 1];
    float k0 = b0 * gamma[QKD + 2 * j] + beta[QKD + 2 * j];
    float k1 = b1 * gamma[QKD + 2 * j + 1] + beta[QKD + 2 * j + 1];
    float s = sn[(size_t)t * 64 + j];
    float c = cs[(size_t)t * 64 + j];
    int bb = t >> 11, nn = t & (SEQ - 1);
    float km = (mask[(size_t)bb * SEQ + nn] != 0) ? 0.f : 1.f;
    q[(size_t)t * QKD + j]       = __float2bfloat16(q0 * c - q1 * s);
    q[(size_t)t * QKD + 64 + j]  = __float2bfloat16(q1 * c + q0 * s);
    k[(size_t)t * QKD + j]       = __float2bfloat16((k0 * c - k1 * s) * km);
    k[(size_t)t * QKD + 64 + j]  = __float2bfloat16((k1 * c + k0 * s) * km);
}

// ------------- V transpose: uv[:,1024:2048] -> Vt[b][h][n] -------------
__global__ __launch_bounds__(256) void vt_kernel(const __hip_bfloat16* __restrict__ uv,
                                                 __hip_bfloat16* __restrict__ Vt) {
    __shared__ __hip_bfloat16 tile[64][65];
    int n0 = blockIdx.x * 64, h0 = blockIdx.y * 64, b = blockIdx.z;
    #pragma unroll
    for (int i = 0; i < 16; i++) {
        int idx = i * 256 + threadIdx.x;
        int r = idx >> 6, c = idx & 63;
        tile[r][c] = uv[((size_t)(b * SEQ + n0 + r)) * NHID + HID + h0 + c];
    }
    __syncthreads();
    #pragma unroll
    for (int i = 0; i < 16; i++) {
        int idx = i * 256 + threadIdx.x;
        int r = idx >> 6, c = idx & 63;
        Vt[((size_t)b * HID + h0 + r) * SEQ + n0 + c] = tile[c][r];
    }
}

// ---------------- shared MFMA GEMM skeleton ----------------
// C[M][N] = A[M][K] @ Bt[N][K]^T, 128x128 block tile, BK=64, 4 waves (2x2 of 64x64)
// EPI 0: silu(acc + bias[col]) -> bf16       (GEMM1 -> uv)
// EPI 1: relu(acc)^2/32768 -> bf16           (QK^T -> P)
// EPI 2: acc * U[row][col] -> bf16           (PV -> hu)
// EPI 3: acc + bias[col] + X[row][col] -> f32 (final)
template <int EPI>
__global__ __launch_bounds__(256) void gemm_bf16(
    const __hip_bfloat16* __restrict__ A, int lda, long long sA,
    const __hip_bfloat16* __restrict__ Bt, int ldb, long long sB,
    int K,
    const float* __restrict__ bias,
    const __hip_bfloat16* __restrict__ U, int ldu, long long sU,
    const float* __restrict__ Xres, int ldx,
    __hip_bfloat16* __restrict__ Cb, float* __restrict__ Cf, int ldc, long long sC) {
    __shared__ __hip_bfloat16 As[128][72];
    __shared__ __hip_bfloat16 Bs[128][72];

    if (sA) A += (size_t)blockIdx.z * sA;
    if (sB) Bt += (size_t)blockIdx.z * sB;
    if (sC) { if (Cb) Cb += (size_t)blockIdx.z * sC; if (Cf) Cf += (size_t)blockIdx.z * sC; }
    if (U && sU) U += (size_t)blockIdx.z * sU;

    int m0 = blockIdx.x * 128, n0 = blockIdx.y * 128;
    int tid = threadIdx.x, lane = tid & 63, wid = tid >> 6;
    int wr = (wid >> 1) * 64, wc = (wid & 1) * 64;

    floatx4 acc[4][4] = {};

    int row_a = tid >> 3;      // 0..31
    int cv = tid & 7;          // 16B chunk

    for (int kt = 0; kt < K; kt += 64) {
        #pragma unroll
        for (int i = 0; i < 4; i++) {
            int r = row_a + i * 32;
            *(uint4*)&As[r][cv * 8] = *(const uint4*)&A[((size_t)(m0 + r)) * lda + kt + cv * 8];
            *(uint4*)&Bs[r][cv * 8] = *(const uint4*)&Bt[((size_t)(n0 + r)) * ldb + kt + cv * 8];
        }
        __syncthreads();
        #pragma unroll
        for (int ko = 0; ko < 2; ko++) {
            short8 a[4], b[4];
            int rr = lane & 15;
            int kb = ko * 32 + (lane >> 4) * 8;
            #pragma unroll
            for (int m = 0; m < 4; m++) a[m] = *(const short8*)&As[wr + m * 16 + rr][kb];
            #pragma unroll
            for (int n = 0; n < 4; n++) b[n] = *(const short8*)&Bs[wc + n * 16 + rr][kb];
            #pragma unroll
            for (int m = 0; m < 4; m++)
                #pragma unroll
                for (int n = 0; n < 4; n++)
                    acc[m][n] = __builtin_amdgcn_mfma_f32_16x16x32_bf16(a[m], b[n], acc[m][n], 0, 0, 0);
        }
        __syncthreads();
    }

    // epilogue: D row=(lane>>4)*4+i, col=lane&15  [guide m89, verified]
    int r4 = (lane >> 4) * 4, cc = lane & 15;
    #pragma unroll
    for (int m = 0; m < 4; m++) {
        #pragma unroll
        for (int n = 0; n < 4; n++) {
            #pragma unroll
            for (int i = 0; i < 4; i++) {
                int row = m0 + wr + m * 16 + r4 + i;
                int col = n0 + wc + n * 16 + cc;
                float v = acc[m][n][i];
                if (EPI == 0) {
                    v += bias[col];
                    v = v / (1.0f + __expf(-v));
                    Cb[(size_t)row * ldc + col] = __float2bfloat16(v);
                } else if (EPI == 1) {
                    v = v > 0.0f ? v * v * (1.0f / 32768.0f) : 0.0f;
                    Cb[(size_t)row * ldc + col] = __float2bfloat16(v);
                } else if (EPI == 2) {
                    v *= __bfloat162float(U[(size_t)row * ldu + col]);
                    Cb[(size_t)row * ldc + col] = __float2bfloat16(v);
                } else {
                    v += bias[col] + Xres[(size_t)row * ldx + col];
                    Cf[(size_t)row * ldc + col] = v;
                }
            }
        }
    }
}

extern "C" void kernel_launch(void* const* d_in, const int* in_sizes, int n_in,
                              void* d_out, int out_size, void* d_ws, size_t ws_size,
                              hipStream_t stream) {
    const float* x     = (const float*)d_in[0];
    const float* msin  = (const float*)d_in[1];
    const float* mcos  = (const float*)d_in[2];
    const int*   mask  = (const int*)d_in[3];
    const float* lnw   = (const float*)d_in[4];
    const float* lnb   = (const float*)d_in[5];
    const float* Wh    = (const float*)d_in[6];
    const float* bh    = (const float*)d_in[7];
    const float* gamma = (const float*)d_in[8];
    const float* beta  = (const float*)d_in[9];
    const float* Wo    = (const float*)d_in[10];
    const float* bo    = (const float*)d_in[11];
    float* out = (float*)d_out;
    char* ws = (char*)d_ws;

    __hip_bfloat16* xn  = (__hip_bfloat16*)(ws + OFF_XN);
    __hip_bfloat16* WhT = (__hip_bfloat16*)(ws + OFF_WHT);
    __hip_bfloat16* WoT = (__hip_bfloat16*)(ws + OFF_WOT);
    __hip_bfloat16* uv  = (__hip_bfloat16*)(ws + OFF_UV);
    __hip_bfloat16* q   = (__hip_bfloat16*)(ws + OFF_Q);
    __hip_bfloat16* k   = (__hip_bfloat16*)(ws + OFF_K);
    __hip_bfloat16* Vt  = (__hip_bfloat16*)(ws + OFF_VT);
    __hip_bfloat16* P   = (__hip_bfloat16*)(ws + OFF_P);
    __hip_bfloat16* hu  = (__hip_bfloat16*)(ws + OFF_HU);

    // 1. LayerNorm -> xn (bf16)
    ln_kernel<<<TOK, 256, 0, stream>>>(x, lnw, lnb, xn);

    // 2. weight transpose/convert
    cvt_kernel<<<(NHID * DIMC + DIMC * HID + 255) / 256, 256, 0, stream>>>(Wh, Wo, WhT, WoT);

    // 3. GEMM1: uv = silu(xn @ Wh + bh)   [16384 x 2176 x 512]
    gemm_bf16<0><<<dim3(TOK / 128, NHID / 128, 1), 256, 0, stream>>>(
        xn, DIMC, 0, WhT, DIMC, 0, DIMC, bh,
        nullptr, 0, 0, nullptr, 0, uv, nullptr, NHID, 0);

    // 4. q/k with rotary, masked keys zeroed
    qkrot_kernel<<<TOK / 4, 256, 0, stream>>>(uv, msin, mcos, mask, gamma, beta, q, k);

    // 5. V transpose per batch
    vt_kernel<<<dim3(SEQ / 64, HID / 64, BATCH), 256, 0, stream>>>(uv, Vt);

    // 6. P = relu(q @ k^T)^2 / 32768   per batch [2048 x 2048 x 128]
    gemm_bf16<1><<<dim3(SEQ / 128, SEQ / 128, BATCH), 256, 0, stream>>>(
        q, QKD, (long long)SEQ * QKD, k, QKD, (long long)SEQ * QKD, QKD, nullptr,
        nullptr, 0, 0, nullptr, 0, P, nullptr, SEQ, (long long)SEQ * SEQ);

    // 7. hu = (P @ V) * u   per batch [2048 x 1024 x 2048]
    gemm_bf16<2><<<dim3(SEQ / 128, HID / 128, BATCH), 256, 0, stream>>>(
        P, SEQ, (long long)SEQ * SEQ, Vt, SEQ, (long long)HID * SEQ, SEQ, nullptr,
        uv, NHID, (long long)SEQ * NHID, nullptr, 0, hu, nullptr, HID, (long long)SEQ * HID);

    // 8. out = hu @ Wo + bo + x   [16384 x 512 x 1024]
    gemm_bf16<3><<<dim3(TOK / 128, DIMC / 128, 1), 256, 0, stream>>>(
        hu, HID, 0, WoT, HID, 0, HID, bo,
        nullptr, 0, 0, x, DIMC, nullptr, out, DIMC, 0);
}